// Round 1
// baseline (3283.639 us; speedup 1.0000x reference)
//
#include <hip/hip_runtime.h>
#include <math.h>

#define DD 128
#define TRI (DD * (DD + 1) / 2)   // 8256 packed lower-triangle elements

// ---------------------------------------------------------------------------
// Kernel A: per patch p, compute winv[d][p] = 1 / (inv(b_covs[p]))_{dd}
// via Cholesky (A = L L^T) + in-place W = L^{-1}, diag(A^{-1})_c = sum_r W[r][c]^2.
// One block (128 threads) per patch; packed lower triangle in LDS (33 KB).
// Only needed for cov_type == 1 (diagonal).
// ---------------------------------------------------------------------------
__global__ __launch_bounds__(DD) void diag_inv_kernel(
    const float* __restrict__ covs,   // [P][D][D]
    const int*   __restrict__ ctp,    // cov_type (device scalar)
    float*       __restrict__ winv,   // [D][P] output: 1/diag(inv(A_p))
    int P)
{
    const int ct = *ctp;
    if (ct != 1) return;              // uniform across block, before any barrier

    const int p   = blockIdx.x;
    const int tid = threadIdx.x;      // row index
    __shared__ float Lp[TRI];
    __shared__ float diagval;

    const size_t base  = (size_t)p * DD * DD;
    const int    ibase = tid * (tid + 1) / 2;

    // Load lower triangle, row tid (row-major packed). A is symmetric.
    for (int j = 0; j <= tid; ++j)
        Lp[ibase + j] = covs[base + (size_t)tid * DD + j];
    __syncthreads();

    // ---- Phase 1: left-looking Cholesky, thread = row ----
    for (int j = 0; j < DD; ++j) {
        const int jbase = j * (j + 1) / 2;
        float s = Lp[ibase + j];      // lanes tid<j read in-bounds garbage; unused
        #pragma unroll 4
        for (int k = 0; k < j; ++k)
            s -= Lp[ibase + k] * Lp[jbase + k];   // per-lane + broadcast reads
        if (tid == j) diagval = sqrtf(s);
        __syncthreads();
        const float dv = diagval;
        if (tid >= j)
            Lp[ibase + j] = (tid == j) ? dv : s / dv;
        __syncthreads();
    }

    // ---- Phase 2: W = L^{-1} row-by-row, overwriting dead L rows in place ----
    // W[r][c] = (delta_rc - sum_{k=c}^{r-1} L[r][k] * W[k][c]) / L[r][r]
    // thread = column c; acc accumulates diag(A^{-1})_c = sum_r W[r][c]^2
    float acc = 0.0f;
    const int wstart = tid & ~63;     // wave-uniform loop start (lane skip per wave)
    for (int r = 0; r < DD; ++r) {
        const int rbase = r * (r + 1) / 2;
        float s = (tid == r) ? 1.0f : 0.0f;
        #pragma unroll 4
        for (int k = wstart; k < r; ++k) {
            if (k >= tid)             // predicate keeps k wave-uniform (broadcast L[r][k])
                s -= Lp[rbase + k] * Lp[k * (k + 1) / 2 + tid];
        }
        const float w = s / Lp[rbase + r];   // read row r BEFORE overwrite
        __syncthreads();
        if (tid <= r) {
            Lp[rbase + tid] = w;      // W row r replaces dead L row r
            acc += w * w;
        }
        __syncthreads();
    }

    winv[(size_t)tid * P + p] = 1.0f / acc;   // whitening multiplier 1/diag(A^{-1})
}

// ---------------------------------------------------------------------------
// Kernel B: per (b,p) thread — center, whiten, L2-normalize, dot with
// normalized signature. Consecutive threads = consecutive p → coalesced.
// ---------------------------------------------------------------------------
__global__ __launch_bounds__(256) void ace_kernel(
    const float* __restrict__ X,      // [B][D][P]
    const float* __restrict__ bmean,  // [D][P]
    const float* __restrict__ covs,   // [P][D][D] (only used when ct==0)
    const float* __restrict__ sig,    // [D][P]
    const int*   __restrict__ ctp,
    const float* __restrict__ winv,   // [D][P]
    float*       __restrict__ out,    // [B][P]
    int B, int P)
{
    const int ct = *ctp;
    const int g  = blockIdx.x * blockDim.x + threadIdx.x;
    if (g >= B * P) return;
    const int b = g / P;
    const int p = g - b * P;

    const float eps = 1e-12f;
    float dot = 0.0f, nx = 0.0f, ns = 0.0f;

    if (ct == 0) {
        // full: Xw[m] = sum_d Xc[d] * covs[p][m][d]  (reference uses b_covs directly)
        for (int m = 0; m < DD; ++m) {
            float xwm = 0.0f;
            const float* crow = covs + (size_t)p * DD * DD + (size_t)m * DD;
            for (int d = 0; d < DD; ++d) {
                const float xc = X[((size_t)b * DD + d) * P + p] - bmean[(size_t)d * P + p];
                xwm += xc * crow[d];
            }
            const float sg = sig[(size_t)m * P + p];
            nx  += xwm * xwm;
            ns  += sg * sg;
            dot += xwm * sg;
        }
    } else {
        // diagonal (ct==1): w = 1/diag(inv A); isotropic (ct==2): positive scalar
        // cancels under L2 normalization -> w = 1.
        #pragma unroll 4
        for (int d = 0; d < DD; ++d) {
            const float xc = X[((size_t)b * DD + d) * P + p] - bmean[(size_t)d * P + p];
            const float w  = (ct == 1) ? winv[(size_t)d * P + p] : 1.0f;
            const float xw = xc * w;
            const float sg = sig[(size_t)d * P + p];
            nx  += xw * xw;
            ns  += sg * sg;
            dot += xw * sg;
        }
    }

    out[g] = dot / (fmaxf(sqrtf(nx), eps) * fmaxf(sqrtf(ns), eps));
}

// ---------------------------------------------------------------------------
extern "C" void kernel_launch(void* const* d_in, const int* in_sizes, int n_in,
                              void* d_out, int out_size, void* d_ws, size_t ws_size,
                              hipStream_t stream)
{
    const float* X     = (const float*)d_in[0];
    const float* bmean = (const float*)d_in[1];
    const float* covs  = (const float*)d_in[2];
    const float* sig   = (const float*)d_in[3];
    const int*   ctp   = (const int*)d_in[4];

    const int DP = in_sizes[1];       // D*P
    const int P  = DP / DD;           // 3136
    const int B  = in_sizes[0] / DP;  // 32

    float* winv = (float*)d_ws;       // [D][P] scratch, 1.6 MB

    diag_inv_kernel<<<P, DD, 0, stream>>>(covs, ctp, winv, P);

    const int total = B * P;
    ace_kernel<<<(total + 255) / 256, 256, 0, stream>>>(
        X, bmean, covs, sig, ctp, winv, (float*)d_out, B, P);
}

// Round 2
// 2162.682 us; speedup vs baseline: 1.5183x; 1.5183x over previous
//
#include <hip/hip_runtime.h>
#include <math.h>

#define DD   128
#define SROW 132   // row stride in floats: 16B-aligned (132*4=528B), b128-friendly

// ---------------------------------------------------------------------------
// Kernel A: per patch p, compute winv[d][p] = 1 / (inv(b_covs[p]))_{dd}
// Full-square LDS layout (stride 132). Phase 1: left-looking Cholesky, one
// barrier per step (pivot self-dot recomputed redundantly per thread from the
// broadcast row). Phase 2: barrier-free per-column forward substitution
// (L y = e_c); y stored in the upper half of the square, float4 both operands.
// diag(A^{-1})_c = sum_r y_r^2 ; winv = 1/that.
// ---------------------------------------------------------------------------
__global__ __launch_bounds__(DD) void diag_inv_kernel(
    const float* __restrict__ covs,   // [P][D][D]
    const int*   __restrict__ ctp,    // cov_type (device scalar)
    float*       __restrict__ winv,   // [D][P]
    int P)
{
    const int ct = *ctp;
    if (ct != 1) return;              // uniform, before any barrier

    const int p   = blockIdx.x;
    const int tid = threadIdx.x;

    __shared__ __align__(16) float S[DD * SROW];
    __shared__ float invd[DD];

    // ---- Load full 128x128 matrix (coalesced float4 global reads) ----
    const float* Ap = covs + (size_t)p * DD * DD;
    #pragma unroll 8
    for (int sweep = 0; sweep < 32; ++sweep) {
        const int idx = sweep * DD + tid;     // 0..4095 float4 slots
        const int row = idx >> 5;             // 32 float4 per row
        const int c4  = (idx & 31) << 2;
        float4 v = *(const float4*)(Ap + (size_t)row * DD + c4);
        *(float4*)(&S[row * SROW + c4]) = v;
    }
    __syncthreads();

    // ---- Phase 1: left-looking Cholesky (thread = row), 1 barrier/step ----
    float* myrow = &S[tid * SROW];
    for (int j = 0; j < DD; ++j) {
        if (tid >= j) {
            const float* jrow = &S[j * SROW];
            float4 sa = {0.f, 0.f, 0.f, 0.f};  // dot(myrow, jrow)
            float4 da = {0.f, 0.f, 0.f, 0.f};  // dot(jrow, jrow) — pivot self-dot
            const int j4 = j & ~3;
            for (int k = 0; k < j4; k += 4) {
                float4 a = *(const float4*)(myrow + k);
                float4 b = *(const float4*)(jrow + k);
                sa.x += a.x * b.x; sa.y += a.y * b.y;
                sa.z += a.z * b.z; sa.w += a.w * b.w;
                da.x += b.x * b.x; da.y += b.y * b.y;
                da.z += b.z * b.z; da.w += b.w * b.w;
            }
            float ss = (sa.x + sa.y) + (sa.z + sa.w);
            float dd = (da.x + da.y) + (da.z + da.w);
            for (int k = j4; k < j; ++k) {
                float a = myrow[k], b = jrow[k];
                ss += a * b; dd += b * b;
            }
            const float s  = myrow[j] - ss;
            const float d  = jrow[j]  - dd;      // raw diag minus self-dot
            float r = rsqrtf(d);                 // + one Newton step
            r = r * (1.5f - 0.5f * d * r * r);
            if (tid == j) {
                invd[j] = r;                     // 1 / L[j][j]
                // NOTE: S[j][j] left RAW (others read it this step for d)
            } else {
                myrow[j] = s * r;                // L[i][j]
            }
        }
        __syncthreads();                         // covers column j + invd[j]
    }

    // ---- Phase 2: forward substitution L y = e_c (thread = column c) ----
    // y_r stored at S[c][r] (upper half, r>c) and yc at S[c][c] — own row only,
    // so no barriers. All L reads are strictly-lower (finalized, never diag).
    const int c = tid;
    const float yc = invd[c];
    float* crow = &S[c * SROW];
    crow[c] = yc;                                // nobody else reads S[c][c] now
    float acc = yc * yc;
    const int wstart = c & ~63;                  // wave-uniform, 16B-aligned

    for (int r = 1; r < DD; ++r) {
        if (c < r) {
            const float* rrow = &S[r * SROW];
            const float inv_r = invd[r];
            float4 sa = {0.f, 0.f, 0.f, 0.f};
            const int kv = wstart + ((r - wstart) & ~3);
            for (int k = wstart; k < kv; k += 4) {
                float4 l = *(const float4*)(rrow + k);
                float4 y = *(const float4*)(crow + k);
                float y0 = (k + 0 >= c) ? y.x : 0.f;
                float y1 = (k + 1 >= c) ? y.y : 0.f;
                float y2 = (k + 2 >= c) ? y.z : 0.f;
                float y3 = (k + 3 >= c) ? y.w : 0.f;
                sa.x += y0 * l.x; sa.y += y1 * l.y;
                sa.z += y2 * l.z; sa.w += y3 * l.w;
            }
            float s = (sa.x + sa.y) + (sa.z + sa.w);
            for (int k = kv; k < r; ++k) {
                float yv = (k >= c) ? crow[k] : 0.f;
                s += yv * rrow[k];
            }
            const float yr = -s * inv_r;
            crow[r] = yr;
            acc += yr * yr;
        }
    }

    winv[(size_t)c * P + p] = 1.0f / acc;        // whitening multiplier
}

// ---------------------------------------------------------------------------
// Kernel B: per (b,p) thread — center, whiten, L2-normalize, dot with
// normalized signature. Consecutive threads = consecutive p → coalesced.
// ---------------------------------------------------------------------------
__global__ __launch_bounds__(256) void ace_kernel(
    const float* __restrict__ X,      // [B][D][P]
    const float* __restrict__ bmean,  // [D][P]
    const float* __restrict__ covs,   // [P][D][D] (only used when ct==0)
    const float* __restrict__ sig,    // [D][P]
    const int*   __restrict__ ctp,
    const float* __restrict__ winv,   // [D][P]
    float*       __restrict__ out,    // [B][P]
    int B, int P)
{
    const int ct = *ctp;
    const int g  = blockIdx.x * blockDim.x + threadIdx.x;
    if (g >= B * P) return;
    const int b = g / P;
    const int p = g - b * P;

    const float eps = 1e-12f;
    float dot = 0.0f, nx = 0.0f, ns = 0.0f;

    if (ct == 0) {
        for (int m = 0; m < DD; ++m) {
            float xwm = 0.0f;
            const float* crow = covs + (size_t)p * DD * DD + (size_t)m * DD;
            for (int d = 0; d < DD; ++d) {
                const float xc = X[((size_t)b * DD + d) * P + p] - bmean[(size_t)d * P + p];
                xwm += xc * crow[d];
            }
            const float sg = sig[(size_t)m * P + p];
            nx  += xwm * xwm;
            ns  += sg * sg;
            dot += xwm * sg;
        }
    } else {
        #pragma unroll 4
        for (int d = 0; d < DD; ++d) {
            const float xc = X[((size_t)b * DD + d) * P + p] - bmean[(size_t)d * P + p];
            const float w  = (ct == 1) ? winv[(size_t)d * P + p] : 1.0f;
            const float xw = xc * w;
            const float sg = sig[(size_t)d * P + p];
            nx  += xw * xw;
            ns  += sg * sg;
            dot += xw * sg;
        }
    }

    out[g] = dot / (fmaxf(sqrtf(nx), eps) * fmaxf(sqrtf(ns), eps));
}

// ---------------------------------------------------------------------------
extern "C" void kernel_launch(void* const* d_in, const int* in_sizes, int n_in,
                              void* d_out, int out_size, void* d_ws, size_t ws_size,
                              hipStream_t stream)
{
    const float* X     = (const float*)d_in[0];
    const float* bmean = (const float*)d_in[1];
    const float* covs  = (const float*)d_in[2];
    const float* sig   = (const float*)d_in[3];
    const int*   ctp   = (const int*)d_in[4];

    const int DP = in_sizes[1];       // D*P
    const int P  = DP / DD;           // 3136
    const int B  = in_sizes[0] / DP;  // 32

    float* winv = (float*)d_ws;       // [D][P] scratch, 1.6 MB

    diag_inv_kernel<<<P, DD, 0, stream>>>(covs, ctp, winv, P);

    const int total = B * P;
    ace_kernel<<<(total + 255) / 256, 256, 0, stream>>>(
        X, bmean, covs, sig, ctp, winv, (float*)d_out, B, P);
}

// Round 3
// 2073.216 us; speedup vs baseline: 1.5838x; 1.0432x over previous
//
#include <hip/hip_runtime.h>
#include <math.h>

#define DD   128
#define SROW 132   // row stride (floats): mult of 4 for 16B-aligned b128 rows

// ---------------------------------------------------------------------------
// Kernel A: winv[d][p] = 1 / (inv(b_covs[p]))_{dd}  via LDL^T.
// Storage: S[i][k] (k<i) holds c_ik = L_ik * D_k (raw, no division on store).
// Phase 1 (thread = row, 1 barrier/step):
//   s_i = A[i][j] - sum_k c_ik * (c_jk * invD_k);  c_ij = s_i;  D_j = s_j.
// Phase 2 (thread = col c, barrier-free): solve L y = e_c (unit diag),
//   y_r = -sum c_rk * w_k,  w_k = invD_k*y_k stored in own row's upper half.
//   diag(A^{-1})_c = sum y_r * w_r.
// Inner loops chunked by 16 with fully-unrolled bodies -> 12 ds_read_b128
// in flight per chunk (the R2 version exposed full LDS latency every 4 elems).
// ---------------------------------------------------------------------------
__global__ __launch_bounds__(DD) void diag_inv_kernel(
    const float* __restrict__ covs,   // [P][D][D]
    const int*   __restrict__ ctp,
    float*       __restrict__ winv,   // [D][P]
    int P)
{
    const int ct = *ctp;
    if (ct != 1) return;              // uniform, before any barrier

    const int p   = blockIdx.x;
    const int tid = threadIdx.x;

    __shared__ __align__(16) float S[DD * SROW];
    __shared__ __align__(16) float invd[DD];

    // ---- Load full 128x128 (coalesced b128 global reads) ----
    const float* Ap = covs + (size_t)p * DD * DD;
    #pragma unroll 8
    for (int sweep = 0; sweep < 32; ++sweep) {
        const int idx = sweep * DD + tid;     // float4 slot 0..4095
        const int row = idx >> 5;
        const int c4  = (idx & 31) << 2;
        float4 v = *(const float4*)(Ap + (size_t)row * DD + c4);
        *(float4*)(&S[row * SROW + c4]) = v;
    }
    __syncthreads();

    // ---- Phase 1: left-looking LDL^T, one barrier per step ----
    float* myrow = &S[tid * SROW];
    for (int j = 0; j < DD; ++j) {
        if (tid >= j) {
            const float* jrow = &S[j * SROW];
            float4 a4 = {0.f, 0.f, 0.f, 0.f};
            int k = 0;
            for (; k + 16 <= j; k += 16) {            // 16-elem chunks, 12 loads in flight
                float4 m[4], q[4], t[4];
                #pragma unroll
                for (int u = 0; u < 4; ++u) m[u] = *(const float4*)(myrow + k + 4*u);
                #pragma unroll
                for (int u = 0; u < 4; ++u) q[u] = *(const float4*)(jrow + k + 4*u);
                #pragma unroll
                for (int u = 0; u < 4; ++u) t[u] = *(const float4*)(&invd[k + 4*u]);
                #pragma unroll
                for (int u = 0; u < 4; ++u) {
                    a4.x = fmaf(m[u].x, q[u].x * t[u].x, a4.x);
                    a4.y = fmaf(m[u].y, q[u].y * t[u].y, a4.y);
                    a4.z = fmaf(m[u].z, q[u].z * t[u].z, a4.z);
                    a4.w = fmaf(m[u].w, q[u].w * t[u].w, a4.w);
                }
            }
            for (; k + 4 <= j; k += 4) {
                float4 m = *(const float4*)(myrow + k);
                float4 q = *(const float4*)(jrow + k);
                float4 t = *(const float4*)(&invd[k]);
                a4.x = fmaf(m.x, q.x * t.x, a4.x);
                a4.y = fmaf(m.y, q.y * t.y, a4.y);
                a4.z = fmaf(m.z, q.z * t.z, a4.z);
                a4.w = fmaf(m.w, q.w * t.w, a4.w);
            }
            for (; k < j; ++k)
                a4.x = fmaf(myrow[k], jrow[k] * invd[k], a4.x);

            const float s = myrow[j] - ((a4.x + a4.y) + (a4.z + a4.w));
            if (tid == j) invd[j] = 1.0f / s;   // D_j = s (diag slot left as raw A)
            else          myrow[j] = s;         // c_ij = L_ij * D_j
        }
        __syncthreads();                        // publishes column j + invd[j]
    }

    // ---- Phase 2: L y = e_c per column, barrier-free ----
    const int c = tid;
    float* crow = &S[c * SROW];
    const float wc = invd[c];                   // w_c = invD_c * y_c, y_c = 1
    crow[c] = wc;                               // own diag slot; nobody reads S[r][r]
    float acc = wc;                             // y_c * w_c
    const int wstart = c & ~63;                 // wave-uniform, 16B-aligned

    for (int r = 1; r < DD; ++r) {
        if (c < r) {
            const float* rrow = &S[r * SROW];
            float4 a4 = {0.f, 0.f, 0.f, 0.f};
            int k = wstart;
            // chunks that may straddle c: predicate elements k' < c to 0
            for (; k + 16 <= r && k < wstart + 64; k += 16) {
                float4 m[4], l[4];
                #pragma unroll
                for (int u = 0; u < 4; ++u) m[u] = *(const float4*)(crow + k + 4*u);
                #pragma unroll
                for (int u = 0; u < 4; ++u) l[u] = *(const float4*)(rrow + k + 4*u);
                #pragma unroll
                for (int u = 0; u < 4; ++u) {
                    const int kb = k + 4*u;
                    float w0 = (kb + 0 >= c) ? m[u].x : 0.f;
                    float w1 = (kb + 1 >= c) ? m[u].y : 0.f;
                    float w2 = (kb + 2 >= c) ? m[u].z : 0.f;
                    float w3 = (kb + 3 >= c) ? m[u].w : 0.f;
                    a4.x = fmaf(w0, l[u].x, a4.x);
                    a4.y = fmaf(w1, l[u].y, a4.y);
                    a4.z = fmaf(w2, l[u].z, a4.z);
                    a4.w = fmaf(w3, l[u].w, a4.w);
                }
            }
            // clean chunks: k >= wstart+64 > c for every lane in this wave
            for (; k + 16 <= r; k += 16) {
                float4 m[4], l[4];
                #pragma unroll
                for (int u = 0; u < 4; ++u) m[u] = *(const float4*)(crow + k + 4*u);
                #pragma unroll
                for (int u = 0; u < 4; ++u) l[u] = *(const float4*)(rrow + k + 4*u);
                #pragma unroll
                for (int u = 0; u < 4; ++u) {
                    a4.x = fmaf(m[u].x, l[u].x, a4.x);
                    a4.y = fmaf(m[u].y, l[u].y, a4.y);
                    a4.z = fmaf(m[u].z, l[u].z, a4.z);
                    a4.w = fmaf(m[u].w, l[u].w, a4.w);
                }
            }
            for (; k + 4 <= r; k += 4) {
                float4 m = *(const float4*)(crow + k);
                float4 l = *(const float4*)(rrow + k);
                float w0 = (k + 0 >= c) ? m.x : 0.f;
                float w1 = (k + 1 >= c) ? m.y : 0.f;
                float w2 = (k + 2 >= c) ? m.z : 0.f;
                float w3 = (k + 3 >= c) ? m.w : 0.f;
                a4.x = fmaf(w0, l.x, a4.x);
                a4.y = fmaf(w1, l.y, a4.y);
                a4.z = fmaf(w2, l.z, a4.z);
                a4.w = fmaf(w3, l.w, a4.w);
            }
            for (; k < r; ++k) {
                float wv = (k >= c) ? crow[k] : 0.f;
                a4.x = fmaf(wv, rrow[k], a4.x);
            }
            const float y = -((a4.x + a4.y) + (a4.z + a4.w));
            const float w = invd[r] * y;
            crow[r] = w;
            acc = fmaf(y, w, acc);
        }
    }

    winv[(size_t)c * P + p] = 1.0f / acc;
}

// ---------------------------------------------------------------------------
// Kernel B: float4 over p — each thread does 4 consecutive patches.
// ---------------------------------------------------------------------------
__global__ __launch_bounds__(256) void ace_kernel(
    const float* __restrict__ X,      // [B][D][P]
    const float* __restrict__ bmean,  // [D][P]
    const float* __restrict__ covs,   // [P][D][D] (ct==0 only)
    const float* __restrict__ sig,    // [D][P]
    const int*   __restrict__ ctp,
    const float* __restrict__ winv,   // [D][P]
    float*       __restrict__ out,    // [B][P]
    int B, int P)
{
    const int ct = *ctp;
    const int P4 = P >> 2;
    const int g  = blockIdx.x * blockDim.x + threadIdx.x;
    if (g >= B * P4) return;
    const int b  = g / P4;
    const int p4 = (g - b * P4) << 2;

    const float eps = 1e-12f;

    if (ct == 0) {
        // full-cov fallback: scalar per patch
        for (int pi = 0; pi < 4; ++pi) {
            const int p = p4 + pi;
            float dot = 0.f, nx = 0.f, ns = 0.f;
            for (int m = 0; m < DD; ++m) {
                float xwm = 0.f;
                const float* crow = covs + (size_t)p * DD * DD + (size_t)m * DD;
                for (int d = 0; d < DD; ++d) {
                    const float xc = X[((size_t)b * DD + d) * P + p] - bmean[(size_t)d * P + p];
                    xwm = fmaf(xc, crow[d], xwm);
                }
                const float sg = sig[(size_t)m * P + p];
                nx  = fmaf(xwm, xwm, nx);
                ns  = fmaf(sg, sg, ns);
                dot = fmaf(xwm, sg, dot);
            }
            out[(size_t)b * P + p] = dot / (fmaxf(sqrtf(nx), eps) * fmaxf(sqrtf(ns), eps));
        }
        return;
    }

    float4 dot = {0.f,0.f,0.f,0.f}, nx = {0.f,0.f,0.f,0.f}, ns = {0.f,0.f,0.f,0.f};

    if (ct == 1) {
        #pragma unroll 4
        for (int d = 0; d < DD; ++d) {
            const float4 xv = *(const float4*)(X + ((size_t)b * DD + d) * P + p4);
            const float4 mv = *(const float4*)(bmean + (size_t)d * P + p4);
            const float4 wv = *(const float4*)(winv + (size_t)d * P + p4);
            const float4 sg = *(const float4*)(sig + (size_t)d * P + p4);
            const float x0 = (xv.x - mv.x) * wv.x;
            const float x1 = (xv.y - mv.y) * wv.y;
            const float x2 = (xv.z - mv.z) * wv.z;
            const float x3 = (xv.w - mv.w) * wv.w;
            nx.x = fmaf(x0, x0, nx.x); nx.y = fmaf(x1, x1, nx.y);
            nx.z = fmaf(x2, x2, nx.z); nx.w = fmaf(x3, x3, nx.w);
            ns.x = fmaf(sg.x, sg.x, ns.x); ns.y = fmaf(sg.y, sg.y, ns.y);
            ns.z = fmaf(sg.z, sg.z, ns.z); ns.w = fmaf(sg.w, sg.w, ns.w);
            dot.x = fmaf(x0, sg.x, dot.x); dot.y = fmaf(x1, sg.y, dot.y);
            dot.z = fmaf(x2, sg.z, dot.z); dot.w = fmaf(x3, sg.w, dot.w);
        }
    } else {   // ct == 2: positive scalar cancels under normalization
        #pragma unroll 4
        for (int d = 0; d < DD; ++d) {
            const float4 xv = *(const float4*)(X + ((size_t)b * DD + d) * P + p4);
            const float4 mv = *(const float4*)(bmean + (size_t)d * P + p4);
            const float4 sg = *(const float4*)(sig + (size_t)d * P + p4);
            const float x0 = xv.x - mv.x, x1 = xv.y - mv.y;
            const float x2 = xv.z - mv.z, x3 = xv.w - mv.w;
            nx.x = fmaf(x0, x0, nx.x); nx.y = fmaf(x1, x1, nx.y);
            nx.z = fmaf(x2, x2, nx.z); nx.w = fmaf(x3, x3, nx.w);
            ns.x = fmaf(sg.x, sg.x, ns.x); ns.y = fmaf(sg.y, sg.y, ns.y);
            ns.z = fmaf(sg.z, sg.z, ns.z); ns.w = fmaf(sg.w, sg.w, ns.w);
            dot.x = fmaf(x0, sg.x, dot.x); dot.y = fmaf(x1, sg.y, dot.y);
            dot.z = fmaf(x2, sg.z, dot.z); dot.w = fmaf(x3, sg.w, dot.w);
        }
    }

    float4 o;
    o.x = dot.x / (fmaxf(sqrtf(nx.x), eps) * fmaxf(sqrtf(ns.x), eps));
    o.y = dot.y / (fmaxf(sqrtf(nx.y), eps) * fmaxf(sqrtf(ns.y), eps));
    o.z = dot.z / (fmaxf(sqrtf(nx.z), eps) * fmaxf(sqrtf(ns.z), eps));
    o.w = dot.w / (fmaxf(sqrtf(nx.w), eps) * fmaxf(sqrtf(ns.w), eps));
    *(float4*)(out + (size_t)b * P + p4) = o;
}

// ---------------------------------------------------------------------------
extern "C" void kernel_launch(void* const* d_in, const int* in_sizes, int n_in,
                              void* d_out, int out_size, void* d_ws, size_t ws_size,
                              hipStream_t stream)
{
    const float* X     = (const float*)d_in[0];
    const float* bmean = (const float*)d_in[1];
    const float* covs  = (const float*)d_in[2];
    const float* sig   = (const float*)d_in[3];
    const int*   ctp   = (const int*)d_in[4];

    const int DP = in_sizes[1];       // D*P
    const int P  = DP / DD;           // 3136
    const int B  = in_sizes[0] / DP;  // 32

    float* winv = (float*)d_ws;       // [D][P] scratch

    diag_inv_kernel<<<P, DD, 0, stream>>>(covs, ctp, winv, P);

    const int total4 = B * (P >> 2);
    ace_kernel<<<(total4 + 255) / 256, 256, 0, stream>>>(
        X, bmean, covs, sig, ctp, winv, (float*)d_out, B, P);
}

// Round 4
// 1596.454 us; speedup vs baseline: 2.0568x; 1.2986x over previous
//
#include <hip/hip_runtime.h>
#include <math.h>

#define DD   128
#define SROW 132   // row stride (floats): mult of 4 -> all b128 accesses 16B-aligned
#define NB   32
#define NT   256
#define NBLK 4     // DD / NB

// ---------------------------------------------------------------------------
// winv[d][p] = 1 / (inv(b_covs[p]))_{dd}
// Blocked right-looking Cholesky (NB=32) + blocked triangular inversion.
// Register-tiled so LDS traffic is ~0.5 float/FMA instead of 2.0 (R3 was
// LDS-pipe bound at ~240K LDS cycles/matrix). Barriers: ~30 vs 128.
// Layout: S[128][132] in LDS. Lower triangle: A -> L -> (phase 2) W = L^-1.
// W_bb (diag blocks) stored TRANSPOSED in the strict upper triangle of the
// corresponding diag block; diag of W = invd[] kept separately.
// diag(A^-1)_c = sum_r W[r][c]^2 accumulated in registers per column thread.
// ---------------------------------------------------------------------------
__global__ __launch_bounds__(NT) void diag_inv_kernel(
    const float* __restrict__ covs,   // [P][D][D]
    const int*   __restrict__ ctp,
    float*       __restrict__ winv,   // [D][P]
    int P)
{
    const int ct = *ctp;
    if (ct != 1) return;              // uniform, before any barrier

    const int p   = blockIdx.x;
    const int tid = threadIdx.x;

    __shared__ __align__(16) float S[DD * SROW];
    __shared__ __align__(16) float invd[DD];

    // ---- Load full 128x128 (coalesced b128 global reads) ----
    const float* Ap = covs + (size_t)p * DD * DD;
    #pragma unroll
    for (int it = 0; it < 16; ++it) {
        const int idx = it * NT + tid;        // float4 slot 0..4095
        const int row = idx >> 5;
        const int c4  = (idx & 31) << 2;
        *(float4*)(&S[row * SROW + c4]) = *(const float4*)(Ap + (size_t)row * DD + c4);
    }
    __syncthreads();

    // ================= Phase 1: blocked right-looking Cholesky ================
    for (int jb = 0; jb < NBLK; ++jb) {
        const int J = jb * NB;

        // ---- Stage A: factor 32x32 diag block. Wave-0 lanes 0..31, no
        //      barriers inside (intra-wave LDS ordering via lgkmcnt). Pivot
        //      rsqrt computed redundantly per lane from the broadcast row. ----
        if (tid < NB) {
            float* myrow = &S[(J + tid) * SROW + J];
            for (int jj = 0; jj < NB; ++jj) {
                if (tid >= jj) {
                    const float* jrow = &S[(J + jj) * SROW + J];
                    float4 sa = {0,0,0,0}, da = {0,0,0,0};
                    const int j4 = jj & ~3;
                    for (int k = 0; k < j4; k += 4) {
                        float4 a = *(const float4*)(myrow + k);
                        float4 b = *(const float4*)(jrow + k);
                        sa.x = fmaf(a.x,b.x,sa.x); sa.y = fmaf(a.y,b.y,sa.y);
                        sa.z = fmaf(a.z,b.z,sa.z); sa.w = fmaf(a.w,b.w,sa.w);
                        da.x = fmaf(b.x,b.x,da.x); da.y = fmaf(b.y,b.y,da.y);
                        da.z = fmaf(b.z,b.z,da.z); da.w = fmaf(b.w,b.w,da.w);
                    }
                    float s = (sa.x+sa.y)+(sa.z+sa.w);
                    float d = (da.x+da.y)+(da.z+da.w);
                    for (int k = j4; k < jj; ++k) {
                        float a = myrow[k], b = jrow[k];
                        s = fmaf(a,b,s); d = fmaf(b,b,d);
                    }
                    s = myrow[jj] - s;                // pre-pivot value, this row
                    d = jrow[jj]  - d;                // pivot d_jj
                    float r = rsqrtf(d);
                    r = r * (1.5f - 0.5f * d * r * r);   // Newton step
                    if (tid == jj) { invd[J + jj] = r; myrow[jj] = d * r; }  // L_jj
                    else            myrow[jj] = s * r;                       // L_ij
                }
            }
        }
        __syncthreads();

        const int nrows = DD - (J + NB);      // 96, 64, 32, 0
        if (nrows > 0) {
            // ---- Stage B: panel solve. Thread t owns row J+NB+t; 32-wide
            //      segment in registers, fully unrolled; only broadcast reads. --
            if (tid < nrows) {
                float* prow = &S[(J + NB + tid) * SROW + J];
                float a[NB];
                #pragma unroll
                for (int k4 = 0; k4 < NB; k4 += 4) {
                    float4 v = *(const float4*)(prow + k4);
                    a[k4] = v.x; a[k4+1] = v.y; a[k4+2] = v.z; a[k4+3] = v.w;
                }
                #pragma unroll
                for (int jj = 0; jj < NB; ++jj) {
                    const float* jrow = &S[(J + jj) * SROW + J];
                    float sp[4] = {0,0,0,0};
                    #pragma unroll
                    for (int k = 0; k < jj; ++k)
                        sp[k & 3] = fmaf(a[k], jrow[k], sp[k & 3]);
                    a[jj] = (a[jj] - ((sp[0]+sp[1])+(sp[2]+sp[3]))) * invd[J + jj];
                }
                #pragma unroll
                for (int k4 = 0; k4 < NB; k4 += 4) {
                    float4 v = {a[k4], a[k4+1], a[k4+2], a[k4+3]};
                    *(float4*)(prow + k4) = v;
                }
            }
            __syncthreads();

            // ---- Stage C: SYRK trailing update, 4x4 register tiles over the
            //      lower-triangular tile grid. 8 b128 reads per 64 FMA. ----
            const int mt = nrows >> 2;
            const int ntile = mt * (mt + 1) / 2;
            for (int t = tid; t < ntile; t += NT) {
                int bi = (int)((sqrtf(8.0f * (float)t + 1.0f) - 1.0f) * 0.5f);
                while ((bi + 1) * (bi + 2) / 2 <= t) ++bi;
                while (bi * (bi + 1) / 2 > t)       --bi;
                const int bj = t - bi * (bi + 1) / 2;
                const float* arow = &S[(J + NB + 4*bi) * SROW + J];
                const float* brow = &S[(J + NB + 4*bj) * SROW + J];
                float acc[4][4] = {{0,0,0,0},{0,0,0,0},{0,0,0,0},{0,0,0,0}};
                #pragma unroll
                for (int k4 = 0; k4 < NB; k4 += 4) {
                    float4 av[4], bv[4];
                    #pragma unroll
                    for (int r = 0; r < 4; ++r) av[r] = *(const float4*)(arow + r*SROW + k4);
                    #pragma unroll
                    for (int c = 0; c < 4; ++c) bv[c] = *(const float4*)(brow + c*SROW + k4);
                    #pragma unroll
                    for (int r = 0; r < 4; ++r)
                        #pragma unroll
                        for (int c = 0; c < 4; ++c)
                            acc[r][c] = fmaf(av[r].x, bv[c].x,
                                        fmaf(av[r].y, bv[c].y,
                                        fmaf(av[r].z, bv[c].z,
                                        fmaf(av[r].w, bv[c].w, acc[r][c]))));
                }
                #pragma unroll
                for (int r = 0; r < 4; ++r) {
                    float* orow = &S[(J + NB + 4*bi + r) * SROW + (J + NB + 4*bj)];
                    float4 o = *(const float4*)orow;
                    o.x -= acc[r][0]; o.y -= acc[r][1];
                    o.z -= acc[r][2]; o.w -= acc[r][3];
                    *(float4*)orow = o;
                }
            }
            __syncthreads();
        }
    }

    // ============== Phase 2: W = L^{-1}; diag(A^{-1}) = col sums of W^2 =======
    float acc2 = 0.0f;

    // ---- 2a: invert all 4 diag blocks (128 parallel column tasks).
    //      y kept in registers (unrolled); W_bb stored transposed in upper. ----
    if (tid < DD) {
        const int blk = tid >> 5, c = tid & 31, Jb = blk * NB;
        const float* Lb = &S[Jb * SROW + Jb];
        float z[NB];
        #pragma unroll
        for (int kk = 0; kk < NB; ++kk) z[kk] = (kk == c) ? invd[Jb + c] : 0.0f;
        #pragma unroll
        for (int rr = 1; rr < NB; ++rr) {
            float sp[4] = {0,0,0,0};
            #pragma unroll
            for (int k = 0; k < rr; ++k)
                sp[k & 3] = fmaf(Lb[rr * SROW + k], z[k], sp[k & 3]);
            const float s = (sp[0]+sp[1])+(sp[2]+sp[3]);
            if (rr > c) z[rr] = -invd[Jb + rr] * s;
        }
        acc2 = invd[Jb + c] * invd[Jb + c];
        #pragma unroll
        for (int rr = 1; rr < NB; ++rr)
            if (rr > c) {
                acc2 = fmaf(z[rr], z[rr], acc2);
                S[(Jb + c) * SROW + (Jb + rr)] = z[rr];   // transposed store
            }
    }
    __syncthreads();

    // ---- 2b: block-rows i=1..3: M_ij = sum_k L_ik W_kj (register tiles),
    //      then solve L_ii W_ij = -M_ij per column. ----
    for (int i = 1; i < NBLK; ++i) {
        const int Ji = i * NB;
        const int jblk = tid >> 6;
        const int tt = tid & 63, tr = tt >> 3, tc = tt & 7;
        float mt[4][4] = {{0,0,0,0},{0,0,0,0},{0,0,0,0},{0,0,0,0}};
        if (tid < i * 64) {
            const int Jj = jblk * NB;
            const float* Lrow0 = &S[(Ji + 4*tr) * SROW + Jj];
            // k == jblk term: W_jj lower-tri via transposed rows + invd diag
            {
                const float* Wt0 = &S[(Jj + 4*tc) * SROW + Jj];
                #pragma unroll
                for (int k4 = 0; k4 < NB; k4 += 4) {
                    float4 lv[4], wv[4];
                    #pragma unroll
                    for (int r = 0; r < 4; ++r) lv[r] = *(const float4*)(Lrow0 + r*SROW + k4);
                    #pragma unroll
                    for (int c = 0; c < 4; ++c) {
                        wv[c] = *(const float4*)(Wt0 + c*SROW + k4);
                        const int cl = 4*tc + c;
                        wv[c].x = (k4 + 0 > cl) ? wv[c].x : 0.0f;
                        wv[c].y = (k4 + 1 > cl) ? wv[c].y : 0.0f;
                        wv[c].z = (k4 + 2 > cl) ? wv[c].z : 0.0f;
                        wv[c].w = (k4 + 3 > cl) ? wv[c].w : 0.0f;
                    }
                    #pragma unroll
                    for (int r = 0; r < 4; ++r)
                        #pragma unroll
                        for (int c = 0; c < 4; ++c)
                            mt[r][c] = fmaf(lv[r].x, wv[c].x,
                                       fmaf(lv[r].y, wv[c].y,
                                       fmaf(lv[r].z, wv[c].z,
                                       fmaf(lv[r].w, wv[c].w, mt[r][c]))));
                }
                const float4 iv = *(const float4*)(&invd[Jj + 4*tc]);
                #pragma unroll
                for (int r = 0; r < 4; ++r) {
                    const float4 ld = *(const float4*)(Lrow0 + r*SROW + 4*tc);
                    mt[r][0] = fmaf(ld.x, iv.x, mt[r][0]);
                    mt[r][1] = fmaf(ld.y, iv.y, mt[r][1]);
                    mt[r][2] = fmaf(ld.z, iv.z, mt[r][2]);
                    mt[r][3] = fmaf(ld.w, iv.w, mt[r][3]);
                }
            }
            // k in (jblk, i): plain GEMM terms with row-major W_kj
            for (int k = jblk + 1; k < i; ++k) {
                const int Jk = k * NB;
                const float* La = &S[(Ji + 4*tr) * SROW + Jk];
                const float* Wb = &S[Jk * SROW + jblk * NB + 4*tc];
                #pragma unroll
                for (int k4 = 0; k4 < NB; k4 += 4) {
                    float4 lv[4], wv[4];
                    #pragma unroll
                    for (int r = 0; r < 4; ++r) lv[r] = *(const float4*)(La + r*SROW + k4);
                    #pragma unroll
                    for (int u = 0; u < 4; ++u) wv[u] = *(const float4*)(Wb + (k4 + u)*SROW);
                    #pragma unroll
                    for (int r = 0; r < 4; ++r) {
                        mt[r][0] = fmaf(lv[r].x, wv[0].x, fmaf(lv[r].y, wv[1].x,
                                   fmaf(lv[r].z, wv[2].x, fmaf(lv[r].w, wv[3].x, mt[r][0]))));
                        mt[r][1] = fmaf(lv[r].x, wv[0].y, fmaf(lv[r].y, wv[1].y,
                                   fmaf(lv[r].z, wv[2].y, fmaf(lv[r].w, wv[3].y, mt[r][1]))));
                        mt[r][2] = fmaf(lv[r].x, wv[0].z, fmaf(lv[r].y, wv[1].z,
                                   fmaf(lv[r].z, wv[2].z, fmaf(lv[r].w, wv[3].z, mt[r][2]))));
                        mt[r][3] = fmaf(lv[r].x, wv[0].w, fmaf(lv[r].y, wv[1].w,
                                   fmaf(lv[r].z, wv[2].w, fmaf(lv[r].w, wv[3].w, mt[r][3]))));
                    }
                }
            }
        }
        __syncthreads();                       // all M reads of L_i* done
        if (tid < i * 64) {
            const int Jj = jblk * NB;
            #pragma unroll
            for (int r = 0; r < 4; ++r) {
                float4 o = {mt[r][0], mt[r][1], mt[r][2], mt[r][3]};
                *(float4*)(&S[(Ji + 4*tr + r) * SROW + Jj + 4*tc]) = o;
            }
        }
        __syncthreads();                       // M visible
        // per-column forward solve: L_ii y = -M[:,cc]; overwrite M with W_ij
        if (tid < i * NB) {
            const int j = tid >> 5, cc = tid & 31, Jj = j * NB;
            const float* Li = &S[Ji * SROW + Ji];
            float z[NB];
            #pragma unroll
            for (int rr = 0; rr < NB; ++rr) z[rr] = S[(Ji + rr) * SROW + Jj + cc];
            #pragma unroll
            for (int rr = 0; rr < NB; ++rr) {
                float sp[4] = {0,0,0,0};
                #pragma unroll
                for (int k = 0; k < rr; ++k)
                    sp[k & 3] = fmaf(Li[rr * SROW + k], z[k], sp[k & 3]);
                z[rr] = -invd[Ji + rr] * (z[rr] + ((sp[0]+sp[1])+(sp[2]+sp[3])));
                acc2 = fmaf(z[rr], z[rr], acc2);
            }
            #pragma unroll
            for (int rr = 0; rr < NB; ++rr) S[(Ji + rr) * SROW + Jj + cc] = z[rr];
        }
        __syncthreads();                       // W_ij visible for next block-row
    }

    if (tid < DD) winv[(size_t)tid * P + p] = 1.0f / acc2;
}

// ---------------------------------------------------------------------------
// Kernel B: float4 over p — each thread does 4 consecutive patches.
// ---------------------------------------------------------------------------
__global__ __launch_bounds__(256) void ace_kernel(
    const float* __restrict__ X,      // [B][D][P]
    const float* __restrict__ bmean,  // [D][P]
    const float* __restrict__ covs,   // [P][D][D] (ct==0 only)
    const float* __restrict__ sig,    // [D][P]
    const int*   __restrict__ ctp,
    const float* __restrict__ winv,   // [D][P]
    float*       __restrict__ out,    // [B][P]
    int B, int P)
{
    const int ct = *ctp;
    const int P4 = P >> 2;
    const int g  = blockIdx.x * blockDim.x + threadIdx.x;
    if (g >= B * P4) return;
    const int b  = g / P4;
    const int p4 = (g - b * P4) << 2;

    const float eps = 1e-12f;

    if (ct == 0) {
        for (int pi = 0; pi < 4; ++pi) {
            const int p = p4 + pi;
            float dot = 0.f, nx = 0.f, ns = 0.f;
            for (int m = 0; m < DD; ++m) {
                float xwm = 0.f;
                const float* crow = covs + (size_t)p * DD * DD + (size_t)m * DD;
                for (int d = 0; d < DD; ++d) {
                    const float xc = X[((size_t)b * DD + d) * P + p] - bmean[(size_t)d * P + p];
                    xwm = fmaf(xc, crow[d], xwm);
                }
                const float sg = sig[(size_t)m * P + p];
                nx  = fmaf(xwm, xwm, nx);
                ns  = fmaf(sg, sg, ns);
                dot = fmaf(xwm, sg, dot);
            }
            out[(size_t)b * P + p] = dot / (fmaxf(sqrtf(nx), eps) * fmaxf(sqrtf(ns), eps));
        }
        return;
    }

    float4 dot = {0.f,0.f,0.f,0.f}, nx = {0.f,0.f,0.f,0.f}, ns = {0.f,0.f,0.f,0.f};

    if (ct == 1) {
        #pragma unroll 4
        for (int d = 0; d < DD; ++d) {
            const float4 xv = *(const float4*)(X + ((size_t)b * DD + d) * P + p4);
            const float4 mv = *(const float4*)(bmean + (size_t)d * P + p4);
            const float4 wv = *(const float4*)(winv + (size_t)d * P + p4);
            const float4 sg = *(const float4*)(sig + (size_t)d * P + p4);
            const float x0 = (xv.x - mv.x) * wv.x;
            const float x1 = (xv.y - mv.y) * wv.y;
            const float x2 = (xv.z - mv.z) * wv.z;
            const float x3 = (xv.w - mv.w) * wv.w;
            nx.x = fmaf(x0, x0, nx.x); nx.y = fmaf(x1, x1, nx.y);
            nx.z = fmaf(x2, x2, nx.z); nx.w = fmaf(x3, x3, nx.w);
            ns.x = fmaf(sg.x, sg.x, ns.x); ns.y = fmaf(sg.y, sg.y, ns.y);
            ns.z = fmaf(sg.z, sg.z, ns.z); ns.w = fmaf(sg.w, sg.w, ns.w);
            dot.x = fmaf(x0, sg.x, dot.x); dot.y = fmaf(x1, sg.y, dot.y);
            dot.z = fmaf(x2, sg.z, dot.z); dot.w = fmaf(x3, sg.w, dot.w);
        }
    } else {
        #pragma unroll 4
        for (int d = 0; d < DD; ++d) {
            const float4 xv = *(const float4*)(X + ((size_t)b * DD + d) * P + p4);
            const float4 mv = *(const float4*)(bmean + (size_t)d * P + p4);
            const float4 sg = *(const float4*)(sig + (size_t)d * P + p4);
            const float x0 = xv.x - mv.x, x1 = xv.y - mv.y;
            const float x2 = xv.z - mv.z, x3 = xv.w - mv.w;
            nx.x = fmaf(x0, x0, nx.x); nx.y = fmaf(x1, x1, nx.y);
            nx.z = fmaf(x2, x2, nx.z); nx.w = fmaf(x3, x3, nx.w);
            ns.x = fmaf(sg.x, sg.x, ns.x); ns.y = fmaf(sg.y, sg.y, ns.y);
            ns.z = fmaf(sg.z, sg.z, ns.z); ns.w = fmaf(sg.w, sg.w, ns.w);
            dot.x = fmaf(x0, sg.x, dot.x); dot.y = fmaf(x1, sg.y, dot.y);
            dot.z = fmaf(x2, sg.z, dot.z); dot.w = fmaf(x3, sg.w, dot.w);
        }
    }

    float4 o;
    o.x = dot.x / (fmaxf(sqrtf(nx.x), eps) * fmaxf(sqrtf(ns.x), eps));
    o.y = dot.y / (fmaxf(sqrtf(nx.y), eps) * fmaxf(sqrtf(ns.y), eps));
    o.z = dot.z / (fmaxf(sqrtf(nx.z), eps) * fmaxf(sqrtf(ns.z), eps));
    o.w = dot.w / (fmaxf(sqrtf(nx.w), eps) * fmaxf(sqrtf(ns.w), eps));
    *(float4*)(out + (size_t)b * P + p4) = o;
}

// ---------------------------------------------------------------------------
extern "C" void kernel_launch(void* const* d_in, const int* in_sizes, int n_in,
                              void* d_out, int out_size, void* d_ws, size_t ws_size,
                              hipStream_t stream)
{
    const float* X     = (const float*)d_in[0];
    const float* bmean = (const float*)d_in[1];
    const float* covs  = (const float*)d_in[2];
    const float* sig   = (const float*)d_in[3];
    const int*   ctp   = (const int*)d_in[4];

    const int DP = in_sizes[1];       // D*P
    const int P  = DP / DD;           // 3136
    const int B  = in_sizes[0] / DP;  // 32

    float* winv = (float*)d_ws;       // [D][P] scratch

    diag_inv_kernel<<<P, NT, 0, stream>>>(covs, ctp, winv, P);

    const int total4 = B * (P >> 2);
    ace_kernel<<<(total4 + 255) / 256, 256, 0, stream>>>(
        X, bmean, covs, sig, ctp, winv, (float*)d_out, B, P);
}

// Round 5
// 899.679 us; speedup vs baseline: 3.6498x; 1.7745x over previous
//
#include <hip/hip_runtime.h>
#include <math.h>

#define DD   128
#define NB   32
#define NT   256
#define NBLK 4      // DD / NB
#define SPACK 8448  // rowoff(128) floats = 33.8 KB packed lower triangle

// Packed lower-triangle layout, rows 16B-aligned.
// Row i (group g=i>>2) gets 4*(g+1) float slots; element [i][c] at rowoff(i)+c.
__device__ __forceinline__ int rowoff(int i) {
    const int g = i >> 2, m = i & 3;
    return 8*g*(g+1) + 4*m*(g+1);
}

// mt[r][c] += dot(a[r], b[c])   (both operands k-major in the float4 lanes)
__device__ __forceinline__ void dotacc(float mt[4][4], const float4 a[4], const float4 b[4]) {
    #pragma unroll
    for (int r = 0; r < 4; ++r) {
        #pragma unroll
        for (int c = 0; c < 4; ++c)
            mt[r][c] = fmaf(a[r].x, b[c].x, fmaf(a[r].y, b[c].y,
                       fmaf(a[r].z, b[c].z, fmaf(a[r].w, b[c].w, mt[r][c]))));
    }
}

// mt[r][c] += sum_e a[r](e) * b[e](c)   (a k-major in lanes, b row-major)
__device__ __forceinline__ void gemmacc(float mt[4][4], const float4 a[4], const float4 b[4]) {
    #pragma unroll
    for (int r = 0; r < 4; ++r) {
        mt[r][0] = fmaf(a[r].x, b[0].x, fmaf(a[r].y, b[1].x, fmaf(a[r].z, b[2].x, fmaf(a[r].w, b[3].x, mt[r][0]))));
        mt[r][1] = fmaf(a[r].x, b[0].y, fmaf(a[r].y, b[1].y, fmaf(a[r].z, b[2].y, fmaf(a[r].w, b[3].y, mt[r][1]))));
        mt[r][2] = fmaf(a[r].x, b[0].z, fmaf(a[r].y, b[1].z, fmaf(a[r].z, b[2].z, fmaf(a[r].w, b[3].z, mt[r][2]))));
        mt[r][3] = fmaf(a[r].x, b[0].w, fmaf(a[r].y, b[1].w, fmaf(a[r].z, b[2].w, fmaf(a[r].w, b[3].w, mt[r][3]))));
    }
}

// ---------------------------------------------------------------------------
// winv[d][p] = 1 / (inv(b_covs[p]))_{dd}
// Blocked Cholesky where each 32x32 diag block is factored AND inverted
// immediately (wave 0, in-register); panel solve and the whole triangular
// inversion then become parallel register-tiled GEMMs (no serial solves).
// Packed-triangle LDS (34.8 KB total) + launch_bounds(256,4) -> 4 blocks/CU.
// ---------------------------------------------------------------------------
__global__ __launch_bounds__(NT, 4) void diag_inv_kernel(
    const float* __restrict__ covs,   // [P][D][D]
    const int*   __restrict__ ctp,
    float*       __restrict__ winv,   // [D][P]
    int P)
{
    const int ct = *ctp;
    if (ct != 1) return;              // uniform, before any barrier

    const int p   = blockIdx.x;
    const int tid = threadIdx.x;

    __shared__ __align__(16) float S[SPACK];
    __shared__ __align__(16) float invd[DD];
    __shared__ __align__(16) float colsum[DD];

    // ---- Load lower triangle (row-prefix reads are coalesced) ----
    const float* Ap = covs + (size_t)p * DD * DD;
    #pragma unroll
    for (int it = 0; it < 16; ++it) {
        const int w   = it * NT + tid;       // square float4 slot 0..4095
        const int row = w >> 5;
        const int c4  = w & 31;
        if (c4 <= (row >> 2))                // fills the full allocated row slots
            *(float4*)&S[rowoff(row) + 4*c4] =
                *(const float4*)(Ap + (size_t)row * DD + 4*c4);
    }
    if (tid < DD) colsum[tid] = 0.0f;
    __syncthreads();

    // ================= Phase 1 =================
    for (int jb = 0; jb < NBLK; ++jb) {
        const int J = jb * NB;

        // ---- Stage A: factor diag block (wave-0 lanes 0..31, lockstep) ----
        if (tid < NB) {
            float* myrow = &S[rowoff(J + tid) + J];
            for (int jj = 0; jj < NB; ++jj) {
                if (tid >= jj) {
                    const float* jrow = &S[rowoff(J + jj) + J];
                    float4 sa = {0,0,0,0}, da = {0,0,0,0};
                    const int j4 = jj & ~3;
                    for (int k = 0; k < j4; k += 4) {
                        float4 a = *(const float4*)(myrow + k);
                        float4 b = *(const float4*)(jrow + k);
                        sa.x = fmaf(a.x,b.x,sa.x); sa.y = fmaf(a.y,b.y,sa.y);
                        sa.z = fmaf(a.z,b.z,sa.z); sa.w = fmaf(a.w,b.w,sa.w);
                        da.x = fmaf(b.x,b.x,da.x); da.y = fmaf(b.y,b.y,da.y);
                        da.z = fmaf(b.z,b.z,da.z); da.w = fmaf(b.w,b.w,da.w);
                    }
                    float s = (sa.x+sa.y)+(sa.z+sa.w);
                    float d = (da.x+da.y)+(da.z+da.w);
                    for (int k = j4; k < jj; ++k) {
                        float a = myrow[k], b = jrow[k];
                        s = fmaf(a,b,s); d = fmaf(b,b,d);
                    }
                    s = myrow[jj] - s;
                    d = jrow[jj]  - d;                   // pivot
                    float r = rsqrtf(d);
                    r = r * (1.5f - 0.5f * d * r * r);   // Newton step
                    if (tid == jj) { invd[J + jj] = r; myrow[jj] = d * r; }
                    else            myrow[jj] = s * r;
                }
            }
        }
        // ---- Stage A2: W_bb = L_bb^{-1} (same wave; z in regs; writes after
        //      all reads -> no race). Stored over L_bb incl diag. ----
        if (tid < NB) {
            float z[NB];
            #pragma unroll
            for (int k = 0; k < NB; ++k) z[k] = (k == tid) ? invd[J + tid] : 0.0f;
            #pragma unroll
            for (int rr = 1; rr < NB; ++rr) {
                const float* lrow = &S[rowoff(J + rr) + J];
                float4 a4 = {0,0,0,0};
                #pragma unroll
                for (int k4 = 0; k4 < (rr & ~3); k4 += 4) {
                    float4 l = *(const float4*)(lrow + k4);
                    a4.x = fmaf(l.x, z[k4+0], a4.x);
                    a4.y = fmaf(l.y, z[k4+1], a4.y);
                    a4.z = fmaf(l.z, z[k4+2], a4.z);
                    a4.w = fmaf(l.w, z[k4+3], a4.w);
                }
                float s = (a4.x+a4.y)+(a4.z+a4.w);
                #pragma unroll
                for (int k = (rr & ~3); k < rr; ++k)
                    s = fmaf(lrow[k], z[k], s);
                const float v = -invd[J + rr] * s;
                if (rr > tid) z[rr] = v;
            }
            float cs = 0.0f;
            #pragma unroll
            for (int rr = 0; rr < NB; ++rr) {
                if (rr >= tid) {
                    S[rowoff(J + rr) + J + tid] = z[rr];
                    cs = fmaf(z[rr], z[rr], cs);
                }
            }
            colsum[J + tid] += cs;     // sole writer of this column right now
        }
        __syncthreads();

        const int nrows = DD - (J + NB);      // 96, 64, 32, 0
        if (nrows > 0) {
            // ---- Stage B: panel L_p = A_p * W_bb^T  (parallel GEMM) ----
            const int ntileB = (nrows >> 2) * 8;
            const int tr = tid >> 3, tc = tid & 7;
            float bt[4][4] = {{0,0,0,0},{0,0,0,0},{0,0,0,0},{0,0,0,0}};
            int prB = 0, saB = 0;
            if (tid < ntileB) {
                prB = J + NB + 4*tr;
                saB = 4*((prB >> 2) + 1);
                const float* A0 = &S[rowoff(prB) + J];
                const int wr = J + 4*tc;
                const int sw = 4*((wr >> 2) + 1);
                const float* W0 = &S[rowoff(wr) + J];
                float4 av[4], wv[4];
                for (int k4 = 0; k4 < 4*tc; k4 += 4) {
                    #pragma unroll
                    for (int r = 0; r < 4; ++r) av[r] = *(const float4*)(A0 + r*saB + k4);
                    #pragma unroll
                    for (int c = 0; c < 4; ++c) wv[c] = *(const float4*)(W0 + c*sw + k4);
                    dotacc(bt, av, wv);
                }
                {   // chunk k4 == 4*tc: W[c][k] valid only for k-lane e <= c
                    const int k4 = 4*tc;
                    #pragma unroll
                    for (int r = 0; r < 4; ++r) av[r] = *(const float4*)(A0 + r*saB + k4);
                    #pragma unroll
                    for (int c = 0; c < 4; ++c) wv[c] = *(const float4*)(W0 + c*sw + k4);
                    wv[0].y = wv[0].z = wv[0].w = 0.f;
                    wv[1].z = wv[1].w = 0.f;
                    wv[2].w = 0.f;
                    dotacc(bt, av, wv);
                }
            }
            __syncthreads();               // all reads of A_p done
            if (tid < ntileB) {
                float* O0 = &S[rowoff(prB) + J + 4*tc];
                #pragma unroll
                for (int r = 0; r < 4; ++r) {
                    float4 o = {bt[r][0], bt[r][1], bt[r][2], bt[r][3]};
                    *(float4*)(O0 + r*saB) = o;
                }
            }
            __syncthreads();

            // ---- Stage C: SYRK trailing update ----
            const int mtC = nrows >> 2;
            const int ntileC = mtC * (mtC + 1) / 2;
            for (int t = tid; t < ntileC; t += NT) {
                int bi = (int)((sqrtf(8.0f * (float)t + 1.0f) - 1.0f) * 0.5f);
                while ((bi + 1) * (bi + 2) / 2 <= t) ++bi;
                while (bi * (bi + 1) / 2 > t)       --bi;
                const int bj = t - bi * (bi + 1) / 2;
                const int pi_ = J + NB + 4*bi, pj_ = J + NB + 4*bj;
                const int sa = 4*((pi_ >> 2) + 1), sb = 4*((pj_ >> 2) + 1);
                const float* Ar = &S[rowoff(pi_) + J];
                const float* Br = &S[rowoff(pj_) + J];
                float acc[4][4] = {{0,0,0,0},{0,0,0,0},{0,0,0,0},{0,0,0,0}};
                float4 av[4], bv[4];
                #pragma unroll
                for (int k4 = 0; k4 < NB; k4 += 4) {
                    #pragma unroll
                    for (int r = 0; r < 4; ++r) av[r] = *(const float4*)(Ar + r*sa + k4);
                    #pragma unroll
                    for (int c = 0; c < 4; ++c) bv[c] = *(const float4*)(Br + c*sb + k4);
                    dotacc(acc, av, bv);
                }
                if (bi != bj) {
                    #pragma unroll
                    for (int r = 0; r < 4; ++r) {
                        float* o = &S[rowoff(pi_) + r*sa + pj_];
                        float4 v = *(const float4*)o;
                        v.x -= acc[r][0]; v.y -= acc[r][1];
                        v.z -= acc[r][2]; v.w -= acc[r][3];
                        *(float4*)o = v;
                    }
                } else {     // diagonal tile: guarded scalar RMW (packed layout!)
                    #pragma unroll
                    for (int r = 0; r < 4; ++r)
                        #pragma unroll
                        for (int c = 0; c < 4; ++c)
                            if (4*bj + c <= 4*bi + r)
                                S[rowoff(pi_) + r*sa + pj_ + c] -= acc[r][c];
                }
            }
            __syncthreads();
        }
    }

    // ================= Phase 2: W_ij = -W_ii * (sum_k L_ik W_kj) ============
    for (int i = 1; i < NBLK; ++i) {
        const int Ji = i * NB;
        const int jblk = tid >> 6;
        const int tt = tid & 63, tr = tt >> 3, tc = tt & 7;
        const bool act = (tid < i * 64);
        const int Jj = jblk * NB;
        const int orow = Ji + 4*tr;
        const int so = 4*((orow >> 2) + 1);
        const int obase = rowoff(orow);
        float mt[4][4] = {{0,0,0,0},{0,0,0,0},{0,0,0,0},{0,0,0,0}};

        if (act) {
            float4 lv[4], wv[4];
            {   // k == jblk: triangular W_jj. Valid kappa >= col -> chunk
                // k4==4tc masked (row e keeps cols c<=e), then k4>4tc full.
                const int k4 = 4*tc;
                #pragma unroll
                for (int r = 0; r < 4; ++r) lv[r] = *(const float4*)(&S[obase + r*so + Jj + k4]);
                const int wr = Jj + k4;
                const int sw = 4*((wr >> 2) + 1);
                #pragma unroll
                for (int e = 0; e < 4; ++e) wv[e] = *(const float4*)(&S[rowoff(wr) + e*sw + Jj + 4*tc]);
                wv[0].y = wv[0].z = wv[0].w = 0.f;
                wv[1].z = wv[1].w = 0.f;
                wv[2].w = 0.f;
                gemmacc(mt, lv, wv);
                for (int kk = k4 + 4; kk < NB; kk += 4) {
                    #pragma unroll
                    for (int r = 0; r < 4; ++r) lv[r] = *(const float4*)(&S[obase + r*so + Jj + kk]);
                    const int wr2 = Jj + kk;
                    const int sw2 = 4*((wr2 >> 2) + 1);
                    #pragma unroll
                    for (int e = 0; e < 4; ++e) wv[e] = *(const float4*)(&S[rowoff(wr2) + e*sw2 + Jj + 4*tc]);
                    gemmacc(mt, lv, wv);
                }
            }
            for (int k = jblk + 1; k < i; ++k) {   // full W blocks
                const int Jk = k * NB;
                #pragma unroll
                for (int k4 = 0; k4 < NB; k4 += 4) {
                    #pragma unroll
                    for (int r = 0; r < 4; ++r) lv[r] = *(const float4*)(&S[obase + r*so + Jk + k4]);
                    const int wr = Jk + k4;
                    const int sw = 4*((wr >> 2) + 1);
                    #pragma unroll
                    for (int e = 0; e < 4; ++e) wv[e] = *(const float4*)(&S[rowoff(wr) + e*sw + Jj + 4*tc]);
                    gemmacc(mt, lv, wv);
                }
            }
        }
        __syncthreads();                 // all reads of L row i done
        if (act) {
            #pragma unroll
            for (int r = 0; r < 4; ++r) {
                float4 o = {mt[r][0], mt[r][1], mt[r][2], mt[r][3]};
                *(float4*)(&S[obase + r*so + Jj + 4*tc]) = o;    // M over L_ij
            }
        }
        __syncthreads();
        float wt[4][4] = {{0,0,0,0},{0,0,0,0},{0,0,0,0},{0,0,0,0}};
        if (act) {
            float4 lv[4], mv[4];
            for (int k4 = 0; k4 < 4*tr; k4 += 4) {     // unmasked W_ii chunks
                #pragma unroll
                for (int r = 0; r < 4; ++r) lv[r] = *(const float4*)(&S[obase + r*so + Ji + k4]);
                const int mr = Ji + k4;
                const int sm = 4*((mr >> 2) + 1);
                #pragma unroll
                for (int e = 0; e < 4; ++e) mv[e] = *(const float4*)(&S[rowoff(mr) + e*sm + Jj + 4*tc]);
                gemmacc(wt, lv, mv);
            }
            {   // chunk k4 == 4*tr: W_ii row r valid lanes e <= r
                const int k4 = 4*tr;
                #pragma unroll
                for (int r = 0; r < 4; ++r) lv[r] = *(const float4*)(&S[obase + r*so + Ji + k4]);
                lv[0].y = lv[0].z = lv[0].w = 0.f;
                lv[1].z = lv[1].w = 0.f;
                lv[2].w = 0.f;
                const int mr = Ji + k4;
                const int sm = 4*((mr >> 2) + 1);
                #pragma unroll
                for (int e = 0; e < 4; ++e) mv[e] = *(const float4*)(&S[rowoff(mr) + e*sm + Jj + 4*tc]);
                gemmacc(wt, lv, mv);
            }
            #pragma unroll
            for (int c = 0; c < 4; ++c) {
                float part = 0.f;
                #pragma unroll
                for (int r = 0; r < 4; ++r) {
                    wt[r][c] = -wt[r][c];
                    part = fmaf(wt[r][c], wt[r][c], part);
                }
                atomicAdd(&colsum[Jj + 4*tc + c], part);
            }
        }
        __syncthreads();
        if (act) {
            #pragma unroll
            for (int r = 0; r < 4; ++r) {
                float4 o = {wt[r][0], wt[r][1], wt[r][2], wt[r][3]};
                *(float4*)(&S[obase + r*so + Jj + 4*tc]) = o;    // W over M
            }
        }
        __syncthreads();
    }

    if (tid < DD) winv[(size_t)tid * P + p] = 1.0f / colsum[tid];
}

// ---------------------------------------------------------------------------
// Kernel B: thread per (b,p); 2D grid (13x32=416 blocks) for latency hiding.
// ---------------------------------------------------------------------------
__global__ __launch_bounds__(256) void ace_kernel(
    const float* __restrict__ X,      // [B][D][P]
    const float* __restrict__ bmean,  // [D][P]
    const float* __restrict__ covs,   // [P][D][D] (ct==0 only)
    const float* __restrict__ sig,    // [D][P]
    const int*   __restrict__ ctp,
    const float* __restrict__ winv,   // [D][P]
    float*       __restrict__ out,    // [B][P]
    int B, int P)
{
    const int ct = *ctp;
    const int b = blockIdx.y;
    const int p = blockIdx.x * 256 + threadIdx.x;
    if (p >= P) return;

    const float eps = 1e-12f;

    if (ct == 0) {    // full-cov fallback (correctness path)
        float dot = 0.f, nx = 0.f, ns = 0.f;
        for (int m = 0; m < DD; ++m) {
            float xwm = 0.f;
            const float* crow = covs + (size_t)p * DD * DD + (size_t)m * DD;
            for (int d = 0; d < DD; ++d) {
                const float xc = X[((size_t)b * DD + d) * P + p] - bmean[(size_t)d * P + p];
                xwm = fmaf(xc, crow[d], xwm);
            }
            const float sg = sig[(size_t)m * P + p];
            nx = fmaf(xwm, xwm, nx); ns = fmaf(sg, sg, ns); dot = fmaf(xwm, sg, dot);
        }
        out[(size_t)b * P + p] = dot / (fmaxf(sqrtf(nx), eps) * fmaxf(sqrtf(ns), eps));
        return;
    }

    float dot = 0.f, nx = 0.f, ns = 0.f;
    const size_t bp = (size_t)b * DD * P + p;
    if (ct == 1) {
        #pragma unroll 8
        for (int d = 0; d < DD; ++d) {
            const float xc = X[bp + (size_t)d * P] - bmean[(size_t)d * P + p];
            const float xw = xc * winv[(size_t)d * P + p];
            const float sg = sig[(size_t)d * P + p];
            nx = fmaf(xw, xw, nx); ns = fmaf(sg, sg, ns); dot = fmaf(xw, sg, dot);
        }
    } else {          // ct == 2: positive scalar cancels under normalization
        #pragma unroll 8
        for (int d = 0; d < DD; ++d) {
            const float xc = X[bp + (size_t)d * P] - bmean[(size_t)d * P + p];
            const float sg = sig[(size_t)d * P + p];
            nx = fmaf(xc, xc, nx); ns = fmaf(sg, sg, ns); dot = fmaf(xc, sg, dot);
        }
    }
    out[(size_t)b * P + p] = dot / (fmaxf(sqrtf(nx), eps) * fmaxf(sqrtf(ns), eps));
}

// ---------------------------------------------------------------------------
extern "C" void kernel_launch(void* const* d_in, const int* in_sizes, int n_in,
                              void* d_out, int out_size, void* d_ws, size_t ws_size,
                              hipStream_t stream)
{
    const float* X     = (const float*)d_in[0];
    const float* bmean = (const float*)d_in[1];
    const float* covs  = (const float*)d_in[2];
    const float* sig   = (const float*)d_in[3];
    const int*   ctp   = (const int*)d_in[4];

    const int DP = in_sizes[1];       // D*P
    const int P  = DP / DD;           // 3136
    const int B  = in_sizes[0] / DP;  // 32

    float* winv = (float*)d_ws;       // [D][P] scratch

    diag_inv_kernel<<<P, NT, 0, stream>>>(covs, ctp, winv, P);

    dim3 gace((P + 255) / 256, B);
    ace_kernel<<<gace, 256, 0, stream>>>(
        X, bmean, covs, sig, ctp, winv, (float*)d_out, B, P);
}